// Round 10
// baseline (383.040 us; speedup 1.0000x reference)
//
#include <hip/hip_runtime.h>
#include <hip/hip_bf16.h>
#include <math.h>

// Problem constants (B=2, C=256, H=W=64, D=4, K=9, K2=81)
#define BATCH 2
#define CCH   256
#define HH    64
#define WW    64
#define PIX   (HH*WW)          // 4096
#define K2    81
#define BP_N  (BATCH*PIX)      // 8192

// ---------------------------------------------------------------------------
// NCHW -> NHWC tiled transpose (per batch).  in: [B][C][P]  out: [B][P][C]
// ---------------------------------------------------------------------------
__global__ void k_transpose(const float* __restrict__ in, float* __restrict__ out) {
    __shared__ float tile[32][33];
    int b  = blockIdx.z;
    int p0 = blockIdx.x * 32;
    int c0 = blockIdx.y * 32;
    int tx = threadIdx.x;     // 32
    int ty = threadIdx.y;     // 8
    const float* ib = in  + (size_t)b * CCH * PIX;
    float*       ob = out + (size_t)b * CCH * PIX;
    #pragma unroll
    for (int i = 0; i < 4; i++) {
        int c = c0 + ty + i * 8;
        int p = p0 + tx;
        tile[ty + i * 8][tx] = ib[(size_t)c * PIX + p];
    }
    __syncthreads();
    #pragma unroll
    for (int i = 0; i < 4; i++) {
        int p = p0 + ty + i * 8;
        int c = c0 + tx;
        ob[(size_t)p * CCH + c] = tile[tx][ty + i * 8];
    }
}

// ---------------------------------------------------------------------------
// NHWC -> NCHW tiled transpose: in [B][P][C] -> out [B][C][P] (for alignedN;
// replaces the 5x-amplified scattered store seen in R9's WRITE_SIZE=80MB).
// ---------------------------------------------------------------------------
__global__ void k_transpose_pc(const float* __restrict__ in, float* __restrict__ out) {
    __shared__ float tile[32][33];
    int b  = blockIdx.z;
    int p0 = blockIdx.x * 32;
    int c0 = blockIdx.y * 32;
    int tx = threadIdx.x;     // 32
    int ty = threadIdx.y;     // 8
    const float* ib = in  + (size_t)b * CCH * PIX;
    float*       ob = out + (size_t)b * CCH * PIX;
    #pragma unroll
    for (int i = 0; i < 4; i++) {
        int p = p0 + ty + i * 8;
        int c = c0 + tx;
        tile[ty + i * 8][tx] = ib[(size_t)p * CCH + c];
    }
    __syncthreads();
    #pragma unroll
    for (int i = 0; i < 4; i++) {
        int c = c0 + ty + i * 8;
        int p = p0 + tx;
        ob[(size_t)c * PIX + p] = tile[tx][ty + i * 8];
    }
}

// ---------------------------------------------------------------------------
// Correlation + sum-normalize + assemble — BIT-EXACT recipe (passed R7-R9,
// absmax 16384/19988): per-dot, lane j accumulates c=32t+j (t ascending,
// fmaf); combine = xor-{8,16,4,2,1} butterfly, lane-0 value is the result;
// k-sum sequential ascending; fp32 divide; assemble sequential ascending-k
// FMA.  DO NOT CHANGE ANY ROUNDING.
//
// R10 perf rewrite (bit-identical values): block = 32-pixel half-row,
// grid = 256 (1 block/CU).  Each k=(dy,dx) needs exactly one ref row, so
// rows are staged per-dy into LDS (40px x 256c = 40KB), cutting L2 traffic
// ~7x (11 KB/px vs 81 KB/px).  OOB rows/cols staged as zeros: the FMA chain
// then yields +0 for OOB dots, and phase-3 adds of +-0 leave acc unchanged
// (+0-propagation verified case-by-case) — matching the skip semantics.
// Writes alignedT (NHWC, coalesced) only; alignedN made by k_transpose_pc.
// ---------------------------------------------------------------------------
__global__ __launch_bounds__(256, 1) void k_corr_assemble(
        const float* __restrict__ featT,
        const float* __restrict__ refT,
        float* __restrict__ alignedT) {
    int blk = blockIdx.x;          // 0..255
    int b   = blk >> 7;            // 128 half-rows per batch
    int r   = blk & 127;
    int y   = r >> 1;
    int w0  = (r & 1) * 32;
    int bp0 = (b << 12) + (y << 6) + w0;   // first pixel of tile
    int tid = threadIdx.x;

    __shared__ float s_feat[32][256];      // 32 KB
    __shared__ float s_row[40][256];       // 40 KB
    __shared__ float s_aff[32][K2];        // 10.1 KB
    __shared__ float s_affn[32][K2];       // 10.1 KB
    __shared__ float s_den[32];

    // stage feat rows (contiguous 32 KB)
    const float* fb = featT + ((size_t)bp0 << 8);
    for (int i = tid; i < 32 * 64; i += 256) {
        int px = i >> 6, c4 = i & 63;
        *(float4*)&s_feat[px][c4 << 2] = *(const float4*)(fb + ((size_t)px << 8) + (c4 << 2));
    }
    __syncthreads();

    const float* rb = refT + ((size_t)b << 20);

    int g   = tid >> 5;    // 0..7 (two groups per wave; masks<32 stay in-half)
    int j   = tid & 31;
    int px0 = g << 2;      // group owns pixels px0..px0+3

    // hoist feat fragments: f[p][t] = feat[px0+p][32t+j]
    float f[4][8];
    #pragma unroll
    for (int p = 0; p < 4; p++)
        #pragma unroll
        for (int t = 0; t < 8; t++)
            f[p][t] = s_feat[px0 + p][32 * t + j];

    // ---- Phase 1: dots, one dy (= one ref row) at a time ----
    for (int dy = 0; dy < 9; dy++) {
        int yy = y + dy - 4;
        for (int i = tid; i < 40 * 64; i += 256) {
            int pp = i >> 6, c4 = i & 63;
            int xx = w0 + pp - 4;
            float4 v = {0.f, 0.f, 0.f, 0.f};
            if ((unsigned)yy < 64u && (unsigned)xx < 64u)
                v = *(const float4*)(rb + ((size_t)((yy << 6) | xx) << 8) + (c4 << 2));
            *(float4*)&s_row[pp][c4 << 2] = v;
        }
        __syncthreads();

        float P[4][9];
        #pragma unroll
        for (int p = 0; p < 4; p++)
            #pragma unroll
            for (int dx = 0; dx < 9; dx++) P[p][dx] = 0.f;

        #pragma unroll
        for (int t = 0; t < 8; t++) {
            #pragma unroll
            for (int pp = 0; pp < 12; pp++) {
                float rv = s_row[px0 + pp][32 * t + j];
                #pragma unroll
                for (int p = 0; p < 4; p++) {
                    int dx = pp - p;
                    if (dx >= 0 && dx < 9)
                        P[p][dx] = fmaf(f[p][t], rv, P[p][dx]);
                }
            }
        }
        // exact butterfly per dot; lane 0's value is the recipe's result
        #pragma unroll
        for (int p = 0; p < 4; p++) {
            #pragma unroll
            for (int dx = 0; dx < 9; dx++) {
                float v = P[p][dx];
                v = __fadd_rn(v, __shfl_xor(v, 8));
                v = __fadd_rn(v, __shfl_xor(v, 16));
                v = __fadd_rn(v, __shfl_xor(v, 4));
                v = __fadd_rn(v, __shfl_xor(v, 2));
                v = __fadd_rn(v, __shfl_xor(v, 1));
                if (j == 0) s_aff[px0 + p][dy * 9 + dx] = v;
            }
        }
        __syncthreads();
    }

    // ---- Phase 2: per-pixel sequential ascending-k sum; fp32 divide ----
    if (tid < 32) {
        float s = 0.f;
        for (int k = 0; k < K2; k++) s = __fadd_rn(s, s_aff[tid][k]);
        s_den[tid] = __fadd_rn(s, 1e-7f);
    }
    __syncthreads();
    for (int i = tid; i < 32 * K2; i += 256) {
        int px = i / K2, k = i - px * K2;
        s_affn[px][k] = __fdiv_rn(s_aff[px][k], s_den[px]);
    }
    __syncthreads();

    // ---- Phase 3: assemble.  Thread = channel c, owns all 32 pixel chains.
    // dy outer ascending; pp ascending => dx ascending per chain: exact
    // k-ascending FMA order per (px,c).
    int c = tid;
    float acc[32];
    #pragma unroll
    for (int px = 0; px < 32; px++) acc[px] = 0.f;

    for (int dy = 0; dy < 9; dy++) {
        int yy = y + dy - 4;
        for (int i = tid; i < 40 * 64; i += 256) {
            int pp = i >> 6, c4 = i & 63;
            int xx = w0 + pp - 4;
            float4 v = {0.f, 0.f, 0.f, 0.f};
            if ((unsigned)yy < 64u && (unsigned)xx < 64u)
                v = *(const float4*)(rb + ((size_t)((yy << 6) | xx) << 8) + (c4 << 2));
            *(float4*)&s_row[pp][c4 << 2] = v;
        }
        __syncthreads();

        #pragma unroll
        for (int pp = 0; pp < 40; pp++) {
            float rv = s_row[pp][c];
            #pragma unroll
            for (int dx = 0; dx < 9; dx++) {
                int px = pp - dx;
                if (px >= 0 && px < 32)
                    acc[px] = fmaf(s_affn[px][dy * 9 + dx], rv, acc[px]);
            }
        }
        __syncthreads();
    }

    float* at = alignedT + ((size_t)bp0 << 8);
    #pragma unroll
    for (int px = 0; px < 32; px++)
        at[((size_t)px << 8) + c] = acc[px];
}

// ---------------------------------------------------------------------------
// Conv1: 1x1, 512 -> 256, FP32 (numerics-free stage).  Block = 256 thr,
// 8 pixels.  h1: [BP][256] fp32.
// ---------------------------------------------------------------------------
__global__ void k_conv1(const float* __restrict__ featT,
                        const float* __restrict__ alignedT,
                        const float* __restrict__ w1,
                        const float* __restrict__ b1,
                        float* __restrict__ h1) {
    __shared__ float s_cat[8][512];
    int p0  = blockIdx.x * 8;
    int tid = threadIdx.x;

    for (int i = tid; i < 8 * 512; i += 256) {
        int px = i >> 9;
        int c  = i & 511;
        size_t gp = (size_t)(p0 + px);
        s_cat[px][c] = (c < 256) ? featT[(gp << 8) + c] : alignedT[(gp << 8) + (c - 256)];
    }
    __syncthreads();

    int o = tid;
    float acc[8];
    #pragma unroll
    for (int px = 0; px < 8; px++) acc[px] = 0.f;

    const float* wr = w1 + (size_t)o * 512;
    for (int c = 0; c < 512; c += 4) {
        float4 wv = *(const float4*)(wr + c);
        #pragma unroll
        for (int px = 0; px < 8; px++) {
            float a = acc[px];
            a = fmaf(wv.x, s_cat[px][c + 0], a);
            a = fmaf(wv.y, s_cat[px][c + 1], a);
            a = fmaf(wv.z, s_cat[px][c + 2], a);
            a = fmaf(wv.w, s_cat[px][c + 3], a);
            acc[px] = a;
        }
    }
    float bias = b1[o];
    for (int px = 0; px < 8; px++)
        h1[((size_t)(p0 + px) << 8) + o] = acc[px] + bias;
}

// ---------------------------------------------------------------------------
// w2 [16][256][3][3] (o,c,kk) -> w2t [kk][o][c]  (c contiguous per thread)
// ---------------------------------------------------------------------------
__global__ void k_w2t(const float* __restrict__ w2, float* __restrict__ w2t) {
    int i = blockIdx.x * 256 + threadIdx.x;
    if (i >= 16 * 256 * 9) return;
    int o  = i / 2304;
    int r  = i % 2304;         // c*9 + kk
    int c  = r / 9;
    int kk = r % 9;
    w2t[((size_t)(kk * 16 + o) << 8) + c] = w2[i];
}

// ---------------------------------------------------------------------------
// Conv2: 3x3 pad1, 256 -> 16, FP32, numerics-free.  Tile-GEMM (R9).
// ---------------------------------------------------------------------------
__global__ void k_conv2(const float* __restrict__ h1,
                        const float* __restrict__ w2t,
                        const float* __restrict__ b2,
                        float* __restrict__ h2) {
    __shared__ float s_in[3][34][68];
    int blk = blockIdx.x;          // 0..255
    int b   = blk >> 7;            // 128 half-rows per batch
    int r   = blk & 127;
    int y   = r >> 1;
    int w0  = (r & 1) * 32;
    int tid = threadIdx.x;
    int o   = tid & 15;
    int ps  = tid >> 4;            // 0..15; handles pixels ps and ps+16

    const float* hb = h1 + ((size_t)b << 20);

    float4 a0 = {0.f, 0.f, 0.f, 0.f};
    float4 a1 = {0.f, 0.f, 0.f, 0.f};

    for (int chunk = 0; chunk < 4; chunk++) {
        int c0 = chunk << 6;
        for (int i = tid; i < 3 * 34 * 16; i += 256) {
            int c4 = i & 15;
            int pi = (i >> 4) % 34;
            int ri = (i >> 4) / 34;
            int yy = y + ri - 1;
            int xx = w0 + pi - 1;
            float4 v = {0.f, 0.f, 0.f, 0.f};
            if ((unsigned)yy < 64u && (unsigned)xx < 64u)
                v = *(const float4*)(hb + ((size_t)((yy << 6) | xx) << 8) + c0 + (c4 << 2));
            *(float4*)&s_in[ri][pi][c4 << 2] = v;
        }
        __syncthreads();

        #pragma unroll
        for (int kk = 0; kk < 9; kk++) {
            int ky = kk / 3, kx = kk - ky * 3;
            const float* wp = w2t + (((size_t)(kk * 16 + o)) << 8) + c0;
            #pragma unroll 8
            for (int c4 = 0; c4 < 16; c4++) {
                float4 wv = *(const float4*)(wp + (c4 << 2));
                float4 i0 = *(const float4*)&s_in[ky][ps + kx][c4 << 2];
                float4 i1 = *(const float4*)&s_in[ky][ps + 16 + kx][c4 << 2];
                a0.x = fmaf(wv.x, i0.x, a0.x);
                a0.y = fmaf(wv.y, i0.y, a0.y);
                a0.z = fmaf(wv.z, i0.z, a0.z);
                a0.w = fmaf(wv.w, i0.w, a0.w);
                a1.x = fmaf(wv.x, i1.x, a1.x);
                a1.y = fmaf(wv.y, i1.y, a1.y);
                a1.z = fmaf(wv.z, i1.z, a1.z);
                a1.w = fmaf(wv.w, i1.w, a1.w);
            }
        }
        __syncthreads();
    }

    float bias = b2[o];
    int p0 = (y << 6) + w0;
    size_t bp0 = ((size_t)b << 12) + p0;
    h2[(bp0 + ps) * 16 + o]      = ((a0.x + a0.y) + (a0.z + a0.w)) + bias;
    h2[(bp0 + ps + 16) * 16 + o] = ((a1.x + a1.y) + (a1.z + a1.w)) + bias;
}

// ---------------------------------------------------------------------------
// Conv3: 3x3 pad1, 16 -> 3, FP32, numerics-free.  Thread per pixel.
// ---------------------------------------------------------------------------
__global__ void k_conv3(const float* __restrict__ h2,
                        const float* __restrict__ w3,
                        const float* __restrict__ b3,
                        float* __restrict__ h3) {
    int bp = blockIdx.x * 256 + threadIdx.x;
    if (bp >= BP_N) return;
    int b = bp >> 12;
    int p = bp & 4095;
    int h = p >> 6, w = p & 63;
    const float* hb = h2 + ((size_t)b << 16);   // b*4096*16

    float a0 = 0.f, a1 = 0.f, a2 = 0.f;
    #pragma unroll
    for (int kk = 0; kk < 9; kk++) {
        int ky = kk / 3, kx = kk - ky * 3;
        int y = h + ky - 1, x = w + kx - 1;
        if ((unsigned)y >= 64u || (unsigned)x >= 64u) continue;
        const float* ip = hb + (size_t)((y << 6) | x) * 16;
        #pragma unroll
        for (int c = 0; c < 16; c++) {
            float v = ip[c];
            int wi = c * 9 + kk;
            a0 = fmaf(w3[wi],       v, a0);
            a1 = fmaf(w3[144 + wi], v, a1);
            a2 = fmaf(w3[288 + wi], v, a2);
        }
    }
    h3[(size_t)bp * 3 + 0] = a0 + b3[0];
    h3[(size_t)bp * 3 + 1] = a1 + b3[1];
    h3[(size_t)bp * 3 + 2] = a2 + b3[2];
}

// ---------------------------------------------------------------------------
// Conv4 (3x3, 3 -> 2) + softmax -> (score0, score1), FP32, numerics-free.
// ---------------------------------------------------------------------------
__global__ void k_score(const float* __restrict__ h3,
                        const float* __restrict__ w4,
                        const float* __restrict__ b4,
                        float2* __restrict__ score) {
    int bp = blockIdx.x * 256 + threadIdx.x;
    if (bp >= BP_N) return;
    int b = bp >> 12;
    int p = bp & 4095;
    int h = p >> 6, w = p & 63;
    const float* hb = h3 + (size_t)b * PIX * 3;

    float l0 = 0.f, l1 = 0.f;
    #pragma unroll
    for (int kk = 0; kk < 9; kk++) {
        int ky = kk / 3, kx = kk - ky * 3;
        int y = h + ky - 1, x = w + kx - 1;
        if ((unsigned)y >= 64u || (unsigned)x >= 64u) continue;
        const float* ip = hb + (size_t)((y << 6) | x) * 3;
        #pragma unroll
        for (int c = 0; c < 3; c++) {
            float v = ip[c];
            int wi = c * 9 + kk;
            l0 = fmaf(w4[wi],      v, l0);
            l1 = fmaf(w4[27 + wi], v, l1);
        }
    }
    l0 += b4[0];
    l1 += b4[1];

    float m  = fmaxf(l0, l1);
    float e0 = expf(l0 - m);
    float e1 = expf(l1 - m);
    float s  = e0 + e1;
    score[bp] = make_float2(e0 / s, e1 / s);
}

// ---------------------------------------------------------------------------
// Blend: out = s0*feat + s1*aligned.
// ---------------------------------------------------------------------------
__global__ void k_blend(const float* __restrict__ feat,
                        const float* __restrict__ alignedN,
                        const float2* __restrict__ score,
                        float* __restrict__ out) {
    size_t i = (size_t)blockIdx.x * 256 + threadIdx.x;
    if (i >= (size_t)BATCH * CCH * PIX) return;
    int b = (int)(i >> 20);       // 256*4096 = 2^20
    int p = (int)(i & 4095);
    float2 s = score[(b << 12) + p];
    out[i] = __fadd_rn(__fmul_rn(s.x, feat[i]), __fmul_rn(s.y, alignedN[i]));
}

// ---------------------------------------------------------------------------
extern "C" void kernel_launch(void* const* d_in, const int* in_sizes, int n_in,
                              void* d_out, int out_size, void* d_ws, size_t ws_size,
                              hipStream_t stream) {
    const float* feat     = (const float*)d_in[0];
    const float* feat_ref = (const float*)d_in[1];
    const float* w1 = (const float*)d_in[2];
    const float* b1 = (const float*)d_in[3];
    const float* w2 = (const float*)d_in[4];
    const float* b2 = (const float*)d_in[5];
    const float* w3 = (const float*)d_in[6];
    const float* b3 = (const float*)d_in[7];
    const float* w4 = (const float*)d_in[8];
    const float* b4 = (const float*)d_in[9];
    float* out = (float*)d_out;

    const size_t NCP = (size_t)BATCH * CCH * PIX;   // 2,097,152
    char* wsb = (char*)d_ws;
    float*  featT    = (float*)wsb;   wsb += NCP * 4;               // 8 MB
    float*  refT     = (float*)wsb;   wsb += NCP * 4;               // 8 MB
    float*  alignedT = (float*)wsb;   wsb += NCP * 4;               // 8 MB
    float*  alignedN = (float*)wsb;   wsb += NCP * 4;               // 8 MB
    float*  h1       = (float*)wsb;   wsb += NCP * 4;               // 8 MB
    float*  h2       = (float*)wsb;   wsb += (size_t)BP_N * 16 * 4;
    float*  h3       = (float*)wsb;   wsb += (size_t)BP_N * 3 * 4;
    float2* sc       = (float2*)wsb;  wsb += (size_t)BP_N * 8;
    float*  w2t      = (float*)wsb;   wsb += (size_t)16 * 256 * 9 * 4;

    dim3 tb(32, 8, 1);
    dim3 tg(PIX / 32, CCH / 32, BATCH);
    k_transpose<<<tg, tb, 0, stream>>>(feat, featT);
    k_transpose<<<tg, tb, 0, stream>>>(feat_ref, refT);
    k_w2t<<<144, 256, 0, stream>>>(w2, w2t);

    k_corr_assemble<<<256, 256, 0, stream>>>(featT, refT, alignedT);
    k_transpose_pc<<<tg, tb, 0, stream>>>(alignedT, alignedN);
    k_conv1<<<BP_N / 8, 256, 0, stream>>>(featT, alignedT, w1, b1, h1);
    k_conv2<<<BP_N / 32, 256, 0, stream>>>(h1, w2t, b2, h2);
    k_conv3<<<BP_N / 256, 256, 0, stream>>>(h2, w3, b3, h3);
    k_score<<<BP_N / 256, 256, 0, stream>>>(h3, w4, b4, sc);
    k_blend<<<(int)(NCP / 256), 256, 0, stream>>>(feat, alignedN, sc, out);
}